// Round 18
// baseline (966.519 us; speedup 1.0000x reference)
//
#include <hip/hip_runtime.h>

// Problem dims
#define S_LEN 256
#define B_SZ  512
#define IN_D  512
#define HID_D 1024
#define NA    16
#define LH    256
#define MR    131072           // S*B
#define LOGOFF 2097152         // S*B*A
#define COLCAP 256
#define DEADW  1024            // t=0, active=0, resetAfter=1

typedef __attribute__((ext_vector_type(8))) short bf16x8;
typedef __attribute__((ext_vector_type(4))) short short4v;
typedef __attribute__((ext_vector_type(4))) float f32x4;

__device__ __forceinline__ unsigned short f2b(float f){
  unsigned int u = __builtin_bit_cast(unsigned int, f);
  unsigned int r = (u + 0x7fffu + ((u>>16)&1u)) >> 16;
  return (unsigned short)r;
}
__device__ __forceinline__ float b2f(unsigned short b){
  unsigned int u = ((unsigned int)b)<<16; return __builtin_bit_cast(float,u);
}
__device__ __forceinline__ float sigf(float x){
  float t = exp2f(-1.4426950408889634f*x);
  return __builtin_amdgcn_rcpf(1.0f+t);
}
__device__ __forceinline__ float tanhf_(float x){
  float t = exp2f(2.8853900817779268f*x);
  return 1.0f - 2.0f*__builtin_amdgcn_rcpf(1.0f+t);
}

#define GLDS16(g, lp) __builtin_amdgcn_global_load_lds( \
    (const __attribute__((address_space(1))) unsigned int*)(g), \
    (__attribute__((address_space(3))) unsigned int*)(lp), 16, 0, 0)

// LDS-only barrier: no vmcnt drain.
#define BARRIER_LDS() do { \
    __builtin_amdgcn_sched_barrier(0); \
    asm volatile("s_waitcnt lgkmcnt(0)" ::: "memory"); \
    __builtin_amdgcn_s_barrier(); \
    __builtin_amdgcn_sched_barrier(0); \
  } while(0)

// ---------------- weight prep kernel ----------------
__global__ __launch_bounds__(256) void prep_w(
    const float* __restrict__ W1, const float* __restrict__ Wih,
    const float* __restrict__ bih, const float* __restrict__ Whh,
    const float* __restrict__ bhh, const float* __restrict__ Wpi,
    const float* __restrict__ bpi, const float* __restrict__ Wv,
    const float* __restrict__ bv,
    ushort* __restrict__ W1b, ushort* __restrict__ Awb, ushort* __restrict__ Whhb,
    ushort* __restrict__ Wpvb, float* __restrict__ wr_, float* __restrict__ bsum,
    float* __restrict__ Etab, float* __restrict__ bpv){
  int i = blockIdx.x*256 + threadIdx.x;
  if (i < 524288) W1b[i] = f2b(W1[i]);
  if (i < 1048576){ int n=i>>10, k=i&1023; Awb[i] = f2b(Wih[n*1041+k]); }
  if (i < 262144) Whhb[i] = f2b(Whh[i]);
  if (i < 8192){ int r=i>>8, k=i&255;
    float v = (r<16) ? Wpi[r*256+k] : ((r==16) ? Wv[k] : 0.f);
    Wpvb[i] = f2b(v); }
  if (i < 1024){ wr_[i] = Wih[i*1041+1024]; bsum[i] = bih[i]+bhh[i]; }
  if (i < 16384){ int a=i>>10, n=i&1023; Etab[i] = Wih[n*1041+1025+a]; }
  if (i < 32) bpv[i] = (i<16) ? bpi[i] : ((i==16) ? bv[0] : 0.f);
}

// ---------------- segment builder (LDS-staged dones, R13) ----------------
__global__ __launch_bounds__(256) void build_cols(const int* __restrict__ dones,
                                                  int* __restrict__ vt,
                                                  int* __restrict__ lens){
  extern __shared__ int dl[];            // [256 t][128 b] = 128 KB
  const int b0 = blockIdx.x * 128;
  for (int idx = threadIdx.x; idx < 256*128; idx += 256){
    int tt = idx >> 7, bb = idx & 127;
    dl[tt*128 + bb] = dones[tt*512 + b0 + bb];
  }
  __syncthreads();
  const int bb = threadIdx.x;
  if (bb >= 128) return;
  const int b = b0 + bb;
  const int colbase = (b>>1)*16 + (b&1)*8;
  int cur = 0, curpos = 0;
  for (int t = 0; t < 256; ++t){
    int isStart = (t==0) || (dl[t*128+bb] != 0);
    if (isStart){
      int nc = t>>5; if (nc>7) nc=7;      // cumulative position == t
      if (nc != cur){
        lens[colbase+cur] = curpos;
        for (int j=cur+1;j<nc;++j) lens[colbase+j]=0;
        cur = nc; curpos = 0;
      }
    }
    int rstA = (t==255) || (dl[(t==255?255:(t+1))*128+bb] != 0);
    vt[(colbase+cur)*COLCAP + curpos] = t | (1<<9) | (rstA<<10);
    curpos++;
  }
  lens[colbase+cur] = curpos;
  for (int j=cur+1;j<8;++j) lens[colbase+j]=0;
}

// ---------------- 256x256 bf16 GEMM (R18: single-barrier T3 minimum) ----
// One vmcnt(0)+barrier per K-tile (guide's verified minimum 2-phase recipe):
// stage for kt+1 issued AFTER the previous barrier; vmcnt at iter END drains
// it with the whole read+MFMA phase (~4000 cyc) of slack. Hazards: reads of
// buf[p] complete before their MFMAs -> before the barrier -> before next
// iter's STG(p); barrier also publishes buf[q] for all waves.
template<int K, int EPI>
__global__ __launch_bounds__(512, 2) void gemm256(
    const ushort* __restrict__ A, const ushort* __restrict__ Bm,
    ushort* __restrict__ C,
    const float* __restrict__ e0, const float* __restrict__ e1,
    const float* __restrict__ e2, const float* __restrict__ rew,
    const int* __restrict__ la){
  extern __shared__ char L[];
  const int t = threadIdx.x, w = t>>6, l = t&63, lq = l>>4, lr = l&15;
  const int wr = w>>2, wc = w&3;            // 2 x 4 wave grid
  const int lid = blockIdx.y*4 + blockIdx.x;
  const int xcd = lid & 7, jj = lid >> 3;   // XCD round-robin model
  const int m0 = (xcd*64 + (jj>>2))*256;
  const int n0 = (jj&3)*256;

  const int r0 = t>>3;
  const int c0 = (t&7) ^ (r0&7);
  const ushort* As0 = A  + (size_t)(m0 +       r0)*K + c0*8;
  const ushort* As1 = A  + (size_t)(m0 +  64 + r0)*K + c0*8;
  const ushort* As2 = A  + (size_t)(m0 + 128 + r0)*K + c0*8;
  const ushort* As3 = A  + (size_t)(m0 + 192 + r0)*K + c0*8;
  const ushort* Bs0 = Bm + (size_t)(n0 +       r0)*K + c0*8;
  const ushort* Bs1 = Bm + (size_t)(n0 +  64 + r0)*K + c0*8;
  const ushort* Bs2 = Bm + (size_t)(n0 + 128 + r0)*K + c0*8;
  const ushort* Bs3 = Bm + (size_t)(n0 + 192 + r0)*K + c0*8;

#define SA(p, ko) do{ \
    GLDS16(As0 + (ko), L + (p)*65536 +     0 + t*16); \
    GLDS16(As1 + (ko), L + (p)*65536 +  8192 + t*16); \
    GLDS16(As2 + (ko), L + (p)*65536 + 16384 + t*16); \
    GLDS16(As3 + (ko), L + (p)*65536 + 24576 + t*16); }while(0)
#define SB(p, ko) do{ \
    GLDS16(Bs0 + (ko), L + (p)*65536 + 32768 + t*16); \
    GLDS16(Bs1 + (ko), L + (p)*65536 + 40960 + t*16); \
    GLDS16(Bs2 + (ko), L + (p)*65536 + 49152 + t*16); \
    GLDS16(Bs3 + (ko), L + (p)*65536 + 57344 + t*16); }while(0)
#define LDA(p, mf, ks) (*(const bf16x8*)(L + (p)*65536 + \
    (wr*128 + (mf)*16 + lr)*128 + (((((ks)*4) + lq) ^ (lr&7))<<4)))
#define LDB(p, nf, ks) (*(const bf16x8*)(L + (p)*65536 + 32768 + \
    (wc*64 + (nf)*16 + lr)*128 + (((((ks)*4) + lq) ^ (lr&7))<<4)))

  f32x4 acc[8][4] = {};
  constexpr int NT = K/64;

  // prologue: stage tile 0, drain, publish
  SA(0, 0); SB(0, 0);
  __builtin_amdgcn_sched_barrier(0);
  asm volatile("s_waitcnt vmcnt(0)" ::: "memory");
  __builtin_amdgcn_s_barrier();
  __builtin_amdgcn_sched_barrier(0);

  #pragma unroll
  for (int kt = 0; kt < NT; ++kt){
    const int p = kt&1, q = p^1;
    const bool pf = (kt+1 < NT);
    // stage next tile (post-barrier: all reads of buf[q] from kt-1 are done)
    if (pf){ SA(q, (kt+1)*64); SB(q, (kt+1)*64); }
    __builtin_amdgcn_sched_barrier(0);
    // ksub 0
    bf16x8 af[8], bf[4];
    #pragma unroll
    for (int mf=0;mf<8;++mf) af[mf] = LDA(p, mf, 0);
    #pragma unroll
    for (int nf=0;nf<4;++nf) bf[nf] = LDB(p, nf, 0);
    asm volatile("s_waitcnt lgkmcnt(0)" ::: "memory");
    __builtin_amdgcn_sched_barrier(0);
    __builtin_amdgcn_s_setprio(1);
    #pragma unroll
    for (int mf=0;mf<8;++mf)
      #pragma unroll
      for (int nf=0;nf<4;++nf)
        acc[mf][nf] = __builtin_amdgcn_mfma_f32_16x16x32_bf16(bf[nf], af[mf], acc[mf][nf], 0,0,0);
    __builtin_amdgcn_s_setprio(0);
    // ksub 1
    #pragma unroll
    for (int mf=0;mf<8;++mf) af[mf] = LDA(p, mf, 1);
    #pragma unroll
    for (int nf=0;nf<4;++nf) bf[nf] = LDB(p, nf, 1);
    asm volatile("s_waitcnt lgkmcnt(0)" ::: "memory");
    __builtin_amdgcn_sched_barrier(0);
    __builtin_amdgcn_s_setprio(1);
    #pragma unroll
    for (int mf=0;mf<8;++mf)
      #pragma unroll
      for (int nf=0;nf<4;++nf)
        acc[mf][nf] = __builtin_amdgcn_mfma_f32_16x16x32_bf16(bf[nf], af[mf], acc[mf][nf], 0,0,0);
    __builtin_amdgcn_s_setprio(0);
    // single end-of-iter sync: next tile landed + this tile's reads done
    __builtin_amdgcn_sched_barrier(0);
    asm volatile("s_waitcnt vmcnt(0)" ::: "memory");
    __builtin_amdgcn_s_barrier();
    __builtin_amdgcn_sched_barrier(0);
  }

  // ---- epilogue: LDS-staged coalesced C-write (512B rows, slot^=row&7)
  #pragma unroll
  for (int mf=0; mf<8; ++mf){
    const int row = wr*128 + mf*16 + lr;
    const int m = m0 + row;
    float rv = 0.f; int av = 0;
    if (EPI == 2){ rv = rew[m]; av = la[m]; }
    #pragma unroll
    for (int nf=0; nf<4; ++nf){
      const int nl = wc*64 + nf*16 + lq*4;
      short4v v;
      if (EPI == 1){
        const float4 bn = *(const float4*)&e0[n0 + nl];
        #pragma unroll
        for (int r=0;r<4;++r){
          float vv = acc[mf][nf][r] + ((const float*)&bn)[r];
          vv = vv > 0.f ? vv : 0.01f*vv;
          v[r] = (short)f2b(vv);
        }
      } else {
        const float4 wv = *(const float4*)&e0[n0 + nl];
        const float4 bs = *(const float4*)&e1[n0 + nl];
        const float4 et = *(const float4*)&e2[(size_t)av*1024 + n0 + nl];
        #pragma unroll
        for (int r=0;r<4;++r){
          float vv = acc[mf][nf][r] + rv*((const float*)&wv)[r]
                   + ((const float*)&et)[r] + ((const float*)&bs)[r];
          v[r] = (short)f2b(vv);
        }
      }
      const int slot = nl >> 3;
      const int phys = slot ^ (row & 7);
      *(short4v*)(L + row*512 + phys*16 + (lq&1)*8) = v;
    }
  }
  __builtin_amdgcn_sched_barrier(0);
  asm volatile("s_waitcnt lgkmcnt(0)" ::: "memory");
  __builtin_amdgcn_s_barrier();
  __builtin_amdgcn_sched_barrier(0);
  {
    const int c16 = t & 31;
    #pragma unroll
    for (int j2=0;j2<16;++j2){
      const int row = j2*16 + (t>>5);
      const int phys = c16 ^ (row & 7);
      bf16x8 d = *(const bf16x8*)(L + row*512 + phys*16);
      *(bf16x8*)&C[(size_t)(m0+row)*1024 + n0 + c16*8] = d;
    }
  }
#undef SA
#undef SB
#undef LDA
#undef LDB
}

// ---------------- 128x128 fused gemm1 (f32 x converted in-staging) --------
// R17 race-fixed version (single barrier/iter already; compiler-fenced xr).
template<int K, int EPI>
__global__ __launch_bounds__(512, 4) void gemm128o(
    const float* __restrict__ Xf, const ushort* __restrict__ Abf,
    const ushort* __restrict__ Bm, ushort* __restrict__ C,
    const float* __restrict__ e0, const float* __restrict__ e1,
    const float* __restrict__ e2, const float* __restrict__ rew,
    const int* __restrict__ la){
  __shared__ char L[65536];
  const int t = threadIdx.x, w = t>>6, l = t&63, lq = l>>4, lr = l&15;
  const int wr = w>>2, wc = w&3;            // 2 (m) x 4 (n) wave grid
  const int lid = blockIdx.y*8 + blockIdx.x;
  const int xcd = lid & 7, j = lid >> 3;    // XCD round-robin model
  const int m0 = (xcd*128 + (j>>3))*128;
  const int n0 = (j&7)*128;

  const int r0 = t>>3;
  const int c0 = (t&7) ^ (r0&7);
  const ushort* As0 = Abf + (size_t)(m0 +      r0)*K + c0*8;   // EPI==2 only
  const ushort* As1 = Abf + (size_t)(m0 + 64 + r0)*K + c0*8;
  const ushort* Bs0 = Bm + (size_t)(n0 +      r0)*K + c0*8;
  const ushort* Bs1 = Bm + (size_t)(n0 + 64 + r0)*K + c0*8;
  const float* xp = Xf + (size_t)(m0 + (t>>2))*512 + (t&3)*16;

#define STGA(p, ko) do{ \
    GLDS16(As0 + (ko), L + (p)*32768 +        t*16); \
    GLDS16(As1 + (ko), L + (p)*32768 +  8192 + t*16); }while(0)
#define STGB(p, ko) do{ \
    GLDS16(Bs0 + (ko), L + (p)*32768 + 16384 + t*16); \
    GLDS16(Bs1 + (ko), L + (p)*32768 + 24576 + t*16); }while(0)
#define LDA(p, mf, ks) (*(const bf16x8*)(L + (p)*32768 + \
    (wr*64 + (mf)*16 + lr)*128 + (((((ks)*4) + lq) ^ (lr&7))<<4)))
#define LDB(p, nf, ks) (*(const bf16x8*)(L + (p)*32768 + 16384 + \
    (wc*32 + (nf)*16 + lr)*128 + (((((ks)*4) + lq) ^ (lr&7))<<4)))
#define WRA(p) do{ \
    const int rr = t>>2, cc = t&3; \
    _Pragma("unroll") \
    for (int jw=0;jw<2;++jw){ \
      bf16x8 v; \
      float4 u0 = xr[2*jw], u1 = xr[2*jw+1]; \
      v[0]=(short)f2b(u0.x); v[1]=(short)f2b(u0.y); \
      v[2]=(short)f2b(u0.z); v[3]=(short)f2b(u0.w); \
      v[4]=(short)f2b(u1.x); v[5]=(short)f2b(u1.y); \
      v[6]=(short)f2b(u1.z); v[7]=(short)f2b(u1.w); \
      *(bf16x8*)(L + (p)*32768 + rr*128 + (((2*cc+jw)^(rr&7))<<4)) = v; \
    }}while(0)

  f32x4 acc[4][2] = {};
  constexpr int NT = K/64;
  float4 xr[4];

  if (EPI == 1){
    #pragma unroll
    for (int jx=0;jx<4;++jx) xr[jx] = *(const float4*)(xp + jx*4);
    STGB(0, 0);
    __builtin_amdgcn_sched_barrier(0);
    WRA(0);                                  // compiler waits for xr itself
    asm volatile("s_waitcnt lgkmcnt(0)" ::: "memory");
    asm volatile("s_waitcnt vmcnt(0)" ::: "memory");   // B glds landed
    __builtin_amdgcn_s_barrier();
    __builtin_amdgcn_sched_barrier(0);
  } else {
    STGA(0, 0); STGB(0, 0);
  }

  for (int kt = 0; kt < NT; ++kt){
    const int p = kt&1, q = p^1;
    const bool pf = (kt+1 < NT);
    if (EPI == 1){
      if (pf){
        const float* xn = xp + (kt+1)*64;
        #pragma unroll
        for (int jx=0;jx<4;++jx) xr[jx] = *(const float4*)(xn + jx*4);
        STGB(q, (kt+1)*64);
      }
      __builtin_amdgcn_sched_barrier(0);
      #pragma unroll
      for (int ks=0; ks<2; ++ks){
        bf16x8 af[4], bf[2];
        #pragma unroll
        for (int mf=0;mf<4;++mf) af[mf] = LDA(p, mf, ks);
        #pragma unroll
        for (int nf=0;nf<2;++nf) bf[nf] = LDB(p, nf, ks);
        asm volatile("s_waitcnt lgkmcnt(0)" ::: "memory");
        __builtin_amdgcn_sched_barrier(0);
        __builtin_amdgcn_s_setprio(1);
        #pragma unroll
        for (int mf=0;mf<4;++mf)
          #pragma unroll
          for (int nf=0;nf<2;++nf)
            acc[mf][nf] = __builtin_amdgcn_mfma_f32_16x16x32_bf16(bf[nf], af[mf], acc[mf][nf], 0,0,0);
        __builtin_amdgcn_s_setprio(0);
      }
      __builtin_amdgcn_sched_barrier(0);
      if (pf){
        WRA(q);                              // compiler waits for xr itself
        asm volatile("s_waitcnt lgkmcnt(0)" ::: "memory");
      } else {
        asm volatile("s_waitcnt lgkmcnt(0)" ::: "memory");
      }
      asm volatile("s_waitcnt vmcnt(0)" ::: "memory");  // B(q) glds landed
      __builtin_amdgcn_s_barrier();
      __builtin_amdgcn_sched_barrier(0);
    } else {
      if (pf){ STGA(q, (kt+1)*64); STGB(q, (kt+1)*64); }
      __builtin_amdgcn_sched_barrier(0);
      if (pf) asm volatile("s_waitcnt vmcnt(4)" ::: "memory");
      else    asm volatile("s_waitcnt vmcnt(0)" ::: "memory");
      __builtin_amdgcn_s_barrier();
      __builtin_amdgcn_sched_barrier(0);
      #pragma unroll
      for (int ks=0; ks<2; ++ks){
        bf16x8 af[4], bf[2];
        #pragma unroll
        for (int mf=0;mf<4;++mf) af[mf] = LDA(p, mf, ks);
        #pragma unroll
        for (int nf=0;nf<2;++nf) bf[nf] = LDB(p, nf, ks);
        asm volatile("s_waitcnt lgkmcnt(0)" ::: "memory");
        __builtin_amdgcn_sched_barrier(0);
        __builtin_amdgcn_s_setprio(1);
        #pragma unroll
        for (int mf=0;mf<4;++mf)
          #pragma unroll
          for (int nf=0;nf<2;++nf)
            acc[mf][nf] = __builtin_amdgcn_mfma_f32_16x16x32_bf16(bf[nf], af[mf], acc[mf][nf], 0,0,0);
        __builtin_amdgcn_s_setprio(0);
      }
      __builtin_amdgcn_sched_barrier(0);
      __builtin_amdgcn_s_barrier();
      __builtin_amdgcn_sched_barrier(0);
    }
  }

  // ---- epilogue: LDS-staged coalesced C-write (256B rows)
  #pragma unroll
  for (int mf=0; mf<4; ++mf){
    const int row = wr*64 + mf*16 + lr;
    const int m = m0 + row;
    float rv = 0.f; int av = 0;
    if (EPI == 2){ rv = rew[m]; av = la[m]; }
    #pragma unroll
    for (int nf=0; nf<2; ++nf){
      const int nl = wc*32 + nf*16 + lq*4;
      short4v v;
      if (EPI == 1){
        const float4 bn = *(const float4*)&e0[n0 + nl];
        #pragma unroll
        for (int r=0;r<4;++r){
          float vv = acc[mf][nf][r] + ((const float*)&bn)[r];
          vv = vv > 0.f ? vv : 0.01f*vv;
          v[r] = (short)f2b(vv);
        }
      } else {
        const float4 wv = *(const float4*)&e0[n0 + nl];
        const float4 bs = *(const float4*)&e1[n0 + nl];
        const float4 et = *(const float4*)&e2[(size_t)av*1024 + n0 + nl];
        #pragma unroll
        for (int r=0;r<4;++r){
          float vv = acc[mf][nf][r] + rv*((const float*)&wv)[r]
                   + ((const float*)&et)[r] + ((const float*)&bs)[r];
          v[r] = (short)f2b(vv);
        }
      }
      const int slot = nl >> 3;
      const int phys = slot ^ (row & 15);
      *(short4v*)(L + row*256 + phys*16 + (lq&1)*8) = v;
    }
  }
  __builtin_amdgcn_sched_barrier(0);
  asm volatile("s_waitcnt lgkmcnt(0)" ::: "memory");
  __builtin_amdgcn_s_barrier();
  __builtin_amdgcn_sched_barrier(0);
  {
    const int c16 = t & 15;
    #pragma unroll
    for (int jj=0;jj<4;++jj){
      const int row = jj*32 + (t>>4);
      const int phys = c16 ^ (row & 15);
      bf16x8 d = *(const bf16x8*)(L + row*256 + phys*16);
      *(bf16x8*)&C[(size_t)(m0+row)*1024 + n0 + c16*8] = d;
    }
  }
#undef STGA
#undef STGB
#undef LDA
#undef LDB
#undef WRA
}

// ---------------- recurrent LSTM kernel (segment-parallel) ----------------
#define LW_FR 18
#define HB0 (8*LW_FR*1024)
__global__ __launch_bounds__(512, 2) void lstm_seq(
    const ushort* __restrict__ Whhb, const ushort* __restrict__ gx,
    ushort* __restrict__ hsout, const int* __restrict__ vt,
    const int* __restrict__ lens){
  extern __shared__ char smem[];
  ushort* wlds = (ushort*)smem;
  char* hb = smem + HB0;                 // 16 cols x 256 bf16, XOR-swizzled
  const int t = threadIdx.x, w = t>>6, l = t&63, lq = l>>4, lr = l&15;
  const int g = blockIdx.x;
  const int bcol = 2*g + (lr>>3);        // batch of column lr
  const int cgl = g*16 + lr;             // global column id

  // register weight frags: m<2 -> k0..4 ; m>=2 -> k0..5   (m = gate*2+hi)
  bf16x8 wf[8][6];
  #pragma unroll
  for (int m=0;m<8;++m){
    const size_t rb = (size_t)((m>>1)*256 + w*32 + (m&1)*16 + lr)*256 + lq*8;
    #pragma unroll
    for (int k=0;k<6;++k){
      if (k < ((m<2)?5:6)) wf[m][k] = *(const bf16x8*)&Whhb[rb + (size_t)k*32];
    }
  }
  // Pin: forbid rematerializing these loads inside the step loop.
  #pragma unroll
  for (int m=0;m<8;++m)
    #pragma unroll
    for (int k=0;k<6;++k)
      if (k < ((m<2)?5:6)) asm volatile("" : "+v"(wf[m][k]));

  // LDS weight frags: m<2 -> k5,6,7 ; m>=2 -> k6,7
  #pragma unroll
  for (int m=0;m<8;++m){
    const size_t rb = (size_t)((m>>1)*256 + w*32 + (m&1)*16 + lr)*256 + lq*8;
    #pragma unroll
    for (int kk=0;kk<3;++kk){
      if (kk < ((m<2)?3:2)){
        const int k  = (m<2)?(5+kk):(6+kk);
        const int fi = (m<2)?(m*3+kk):(6+(m-2)*2+kk);
        bf16x8 v = *(const bf16x8*)&Whhb[rb + (size_t)k*32];
        *(bf16x8*)((char*)wlds + ((w*LW_FR + fi)*1024 + l*16)) = v;
      }
    }
  }
  { bf16x8 z = {0,0,0,0,0,0,0,0}; *(bf16x8*)(hb + t*16) = z; }  // zero h

#define LDSFRAG(m,kf) (*(const bf16x8*)((char*)wlds + ((w*LW_FR + ((m)<2 ? ((m)*3+((kf)-5)) : (6+((m)-2)*2+((kf)-6))))*1024 + l*16)))
#define WFRAG(m,kf) (((kf) < (((m)<2)?5:6)) ? wf[m][kf] : LDSFRAG(m,kf))
#define HVREAD(kf) (*(const bf16x8*)(hb + ((lr*512 + (kf)*64 + lq*16) ^ ((lr&7)<<4))))

  const int lenc = lens[cgl];
  int blkLen = 0;
  for (int j=0;j<16;++j){ int v = lens[g*16+j]; blkLen = v>blkLen ? v : blkLen; }
  const int* vtc = vt + (size_t)cgl*COLCAP;
#define ENTW(j) (((j) < lenc) ? vtc[j] : DEADW)

  int e0 = ENTW(0), e1 = ENTW(1);
  const int goff = w*32 + lq*4;
  float c_[2][4] = {};
  uint2 gi[2], gg[2];
  {
    const ushort* gr = gx + ((size_t)((e0 & 511)*512 + bcol))*1024 + goff;
    gi[0]=*(const uint2*)(gr+  0); gi[1]=*(const uint2*)(gr+ 16);
    gg[0]=*(const uint2*)(gr+512); gg[1]=*(const uint2*)(gr+528);
  }
  __syncthreads();

  for (int k = 0; k < blkLen; ++k){
    const int e2 = ENTW(k+2);
    const ushort* grow0 = gx + ((size_t)((e0 & 511)*512 + bcol))*1024 + goff;
    uint2 gf0=*(const uint2*)(grow0+256), gf1=*(const uint2*)(grow0+272);
    uint2 go0=*(const uint2*)(grow0+768), go1=*(const uint2*)(grow0+784);
    // ---- pass 1: i and g gates (m-frags 0,1,4,5)
    f32x4 ai0={},ai1={},ag0={},ag1={};
    #pragma unroll
    for (int kf=0;kf<8;++kf){
      bf16x8 hv = HVREAD(kf);
      ai0 = __builtin_amdgcn_mfma_f32_16x16x32_bf16(WFRAG(0,kf), hv, ai0, 0,0,0);
      ai1 = __builtin_amdgcn_mfma_f32_16x16x32_bf16(WFRAG(1,kf), hv, ai1, 0,0,0);
      ag0 = __builtin_amdgcn_mfma_f32_16x16x32_bf16(WFRAG(4,kf), hv, ag0, 0,0,0);
      ag1 = __builtin_amdgcn_mfma_f32_16x16x32_bf16(WFRAG(5,kf), hv, ag1, 0,0,0);
    }
    float tig[2][4];
    #pragma unroll
    for (int hi=0;hi<2;++hi){
      uint2 ui = gi[hi], ug = gg[hi];
      float xi[4] = { b2f((unsigned short)(ui.x&0xffff)), b2f((unsigned short)(ui.x>>16)),
                      b2f((unsigned short)(ui.y&0xffff)), b2f((unsigned short)(ui.y>>16)) };
      float xg[4] = { b2f((unsigned short)(ug.x&0xffff)), b2f((unsigned short)(ug.x>>16)),
                      b2f((unsigned short)(ug.y&0xffff)), b2f((unsigned short)(ug.y>>16)) };
      #pragma unroll
      for (int r=0;r<4;++r){
        float iv = (hi ? ai1[r] : ai0[r]) + xi[r];
        float gv = (hi ? ag1[r] : ag0[r]) + xg[r];
        tig[hi][r] = sigf(iv) * tanhf_(gv);
      }
    }
    {
      const ushort* grow1 = gx + ((size_t)((e1 & 511)*512 + bcol))*1024 + goff;
      gi[0]=*(const uint2*)(grow1+  0); gi[1]=*(const uint2*)(grow1+ 16);
      gg[0]=*(const uint2*)(grow1+512); gg[1]=*(const uint2*)(grow1+528);
    }
    // ---- pass 2: f and o gates (m-frags 2,3,6,7)
    f32x4 af0={},af1={},ao0={},ao1={};
    #pragma unroll
    for (int kf=0;kf<8;++kf){
      bf16x8 hv = HVREAD(kf);
      af0 = __builtin_amdgcn_mfma_f32_16x16x32_bf16(WFRAG(2,kf), hv, af0, 0,0,0);
      af1 = __builtin_amdgcn_mfma_f32_16x16x32_bf16(WFRAG(3,kf), hv, af1, 0,0,0);
      ao0 = __builtin_amdgcn_mfma_f32_16x16x32_bf16(WFRAG(6,kf), hv, ao0, 0,0,0);
      ao1 = __builtin_amdgcn_mfma_f32_16x16x32_bf16(WFRAG(7,kf), hv, ao1, 0,0,0);
    }
    uint2 hpk[2];
    #pragma unroll
    for (int hi=0;hi<2;++hi){
      uint2 uf = hi ? gf1 : gf0, uo = hi ? go1 : go0;
      float xf[4] = { b2f((unsigned short)(uf.x&0xffff)), b2f((unsigned short)(uf.x>>16)),
                      b2f((unsigned short)(uf.y&0xffff)), b2f((unsigned short)(uf.y>>16)) };
      float xo[4] = { b2f((unsigned short)(uo.x&0xffff)), b2f((unsigned short)(uo.x>>16)),
                      b2f((unsigned short)(uo.y&0xffff)), b2f((unsigned short)(uo.y>>16)) };
      float hv[4];
      #pragma unroll
      for (int r=0;r<4;++r){
        float fv = (hi ? af1[r] : af0[r]) + xf[r];
        float ov = (hi ? ao1[r] : ao0[r]) + xo[r];
        float c = sigf(fv)*c_[hi][r] + tig[hi][r];
        c_[hi][r] = c;
        hv[r] = sigf(ov) * tanhf_(c);
      }
      hpk[hi].x = (unsigned)f2b(hv[0]) | ((unsigned)f2b(hv[1])<<16);
      hpk[hi].y = (unsigned)f2b(hv[2]) | ((unsigned)f2b(hv[3])<<16);
    }
    // ---- store hs (pre-mask) if active
    if (e0 & 512){
      ushort* hp = hsout + ((size_t)((e0 & 511)*512 + bcol))*256 + goff;
      *(uint2*)(hp +  0) = hpk[0];
      *(uint2*)(hp + 16) = hpk[1];
    }
    // ---- segment-boundary reset
    if (e0 & 1024){
      hpk[0].x=0; hpk[0].y=0; hpk[1].x=0; hpk[1].y=0;
      #pragma unroll
      for (int hi=0;hi<2;++hi)
        #pragma unroll
        for (int r=0;r<4;++r) c_[hi][r]=0.f;
    }
    e0 = e1; e1 = e2;
    BARRIER_LDS();   // all h reads of this step complete (no vmcnt drain)
    *(uint2*)(hb + ((lr*512 + w*64 +  0 + lq*8) ^ ((lr&7)<<4))) = hpk[0];
    *(uint2*)(hb + ((lr*512 + w*64 + 32 + lq*8) ^ ((lr&7)<<4))) = hpk[1];
    BARRIER_LDS();   // new h visible (no vmcnt drain)
  }
}

// ---------------- head: logits/values ----------------
__global__ __launch_bounds__(256) void head(
    const ushort* __restrict__ hs, const ushort* __restrict__ Wpv,
    const float* __restrict__ bpv, float* __restrict__ out){
  const int t = threadIdx.x, w = t>>6, l = t&63, lq = l>>4, lr = l&15;
  const int m0 = blockIdx.x*64 + w*16;
  f32x4 acc[2] = {};
  #pragma unroll
  for (int kf=0;kf<8;++kf){
    bf16x8 a = *(const bf16x8*)&hs[(size_t)(m0+lr)*256 + kf*32 + lq*8];
    #pragma unroll
    for (int j=0;j<2;++j){
      bf16x8 b = *(const bf16x8*)&Wpv[(size_t)(j*16+lr)*256 + kf*32 + lq*8];
      acc[j] = __builtin_amdgcn_mfma_f32_16x16x32_bf16(a, b, acc[j], 0,0,0);
    }
  }
  #pragma unroll
  for (int j=0;j<2;++j){
    const int n = j*16 + lr;
    if (n > 16) continue;
    const float bn = bpv[n];
    #pragma unroll
    for (int r=0;r<4;++r){
      const int m = m0 + lq*4 + r;
      float v = acc[j][r] + bn;
      if (n < 16) out[(size_t)m*16 + n] = v;
      else        out[(size_t)LOGOFF + m] = v;
    }
  }
}

// ---------------- launch ----------------
extern "C" void kernel_launch(void* const* d_in, const int* in_sizes, int n_in,
                              void* d_out, int out_size, void* d_ws, size_t ws_size,
                              hipStream_t stream) {
  const float* x    = (const float*)d_in[0];
  const float* rew  = (const float*)d_in[1];
  const float* W1   = (const float*)d_in[3];
  const float* b1   = (const float*)d_in[4];
  const float* Wih  = (const float*)d_in[5];
  const float* bih  = (const float*)d_in[6];
  const float* Whh  = (const float*)d_in[7];
  const float* bhh  = (const float*)d_in[8];
  const float* Wpi  = (const float*)d_in[9];
  const float* bpi  = (const float*)d_in[10];
  const float* Wv   = (const float*)d_in[11];
  const float* bv   = (const float*)d_in[12];
  const int*   la   = (const int*)d_in[13];
  const int*   dns  = (const int*)d_in[14];
  float* out = (float*)d_out;
  char* ws = (char*)d_ws;

  int*    vt   = (int*)(ws + 0LL);             // 4096 cols x 256 x 4B = 4 MB
  int*    lens = (int*)(ws + 4194304LL);       // 16 KB
  ushort* h1   = (ushort*)(ws + 134217728LL);
  ushort* gx   = (ushort*)(ws + 402653184LL);
  ushort* hs   = (ushort*)(ws + 671088640LL);
  ushort* W1b  = (ushort*)(ws + 738197504LL);
  ushort* Awb  = (ushort*)(ws + 739246080LL);
  ushort* Whhb = (ushort*)(ws + 741343232LL);
  ushort* Wpvb = (ushort*)(ws + 741867520LL);
  float*  wr_  = (float*)(ws + 741883904LL);
  float*  bsum = (float*)(ws + 741888000LL);
  float*  Etab = (float*)(ws + 741892096LL);
  float*  bpv  = (float*)(ws + 741957632LL);

  (void)hipFuncSetAttribute((const void*)lstm_seq,
                            hipFuncAttributeMaxDynamicSharedMemorySize, 155648);
  (void)hipFuncSetAttribute((const void*)build_cols,
                            hipFuncAttributeMaxDynamicSharedMemorySize, 131072);
  auto g2 = &gemm256<1024,2>;
  (void)hipFuncSetAttribute((const void*)g2,
                            hipFuncAttributeMaxDynamicSharedMemorySize, 131072);

  prep_w<<<4096, 256, 0, stream>>>(W1, Wih, bih, Whh, bhh, Wpi, bpi, Wv, bv,
                                   W1b, Awb, Whhb, Wpvb, wr_, bsum, Etab, bpv);
  build_cols<<<4, 256, 131072, stream>>>(dns, vt, lens);
  gemm128o<512,1><<<dim3(8,1024), 512, 0, stream>>>(x, nullptr, W1b, h1, b1,
                                                    nullptr, nullptr, nullptr, nullptr);
  gemm256<1024,2><<<dim3(4,512), 512, 131072, stream>>>(h1, Awb, gx, wr_,
                                                        bsum, Etab, rew, la);
  lstm_seq<<<256, 512, 155648, stream>>>(Whhb, gx, hs, vt, lens);
  head<<<2048, 256, 0, stream>>>(hs, Wpvb, bpv, out);
}

// Round 19
// 951.338 us; speedup vs baseline: 1.0160x; 1.0160x over previous
//
#include <hip/hip_runtime.h>

// Problem dims
#define S_LEN 256
#define B_SZ  512
#define IN_D  512
#define HID_D 1024
#define NA    16
#define LH    256
#define MR    131072           // S*B
#define LOGOFF 2097152         // S*B*A
#define COLCAP 256
#define DEADW  1024            // t=0, active=0, resetAfter=1

typedef __attribute__((ext_vector_type(8))) short bf16x8;
typedef __attribute__((ext_vector_type(4))) short short4v;
typedef __attribute__((ext_vector_type(4))) float f32x4;

__device__ __forceinline__ unsigned short f2b(float f){
  unsigned int u = __builtin_bit_cast(unsigned int, f);
  unsigned int r = (u + 0x7fffu + ((u>>16)&1u)) >> 16;
  return (unsigned short)r;
}
__device__ __forceinline__ float b2f(unsigned short b){
  unsigned int u = ((unsigned int)b)<<16; return __builtin_bit_cast(float,u);
}
__device__ __forceinline__ float sigf(float x){
  float t = exp2f(-1.4426950408889634f*x);
  return __builtin_amdgcn_rcpf(1.0f+t);
}
__device__ __forceinline__ float tanhf_(float x){
  float t = exp2f(2.8853900817779268f*x);
  return 1.0f - 2.0f*__builtin_amdgcn_rcpf(1.0f+t);
}

#define GLDS16(g, lp) __builtin_amdgcn_global_load_lds( \
    (const __attribute__((address_space(1))) unsigned int*)(g), \
    (__attribute__((address_space(3))) unsigned int*)(lp), 16, 0, 0)

// LDS-only barrier: no vmcnt drain.
#define BARRIER_LDS() do { \
    __builtin_amdgcn_sched_barrier(0); \
    asm volatile("s_waitcnt lgkmcnt(0)" ::: "memory"); \
    __builtin_amdgcn_s_barrier(); \
    __builtin_amdgcn_sched_barrier(0); \
  } while(0)

// ---------------- weight prep kernel ----------------
__global__ __launch_bounds__(256) void prep_w(
    const float* __restrict__ W1, const float* __restrict__ Wih,
    const float* __restrict__ bih, const float* __restrict__ Whh,
    const float* __restrict__ bhh, const float* __restrict__ Wpi,
    const float* __restrict__ bpi, const float* __restrict__ Wv,
    const float* __restrict__ bv,
    ushort* __restrict__ W1b, ushort* __restrict__ Awb, ushort* __restrict__ Whhb,
    ushort* __restrict__ Wpvb, float* __restrict__ wr_, float* __restrict__ bsum,
    float* __restrict__ Etab, float* __restrict__ bpv){
  int i = blockIdx.x*256 + threadIdx.x;
  if (i < 524288) W1b[i] = f2b(W1[i]);
  if (i < 1048576){ int n=i>>10, k=i&1023; Awb[i] = f2b(Wih[n*1041+k]); }
  if (i < 262144) Whhb[i] = f2b(Whh[i]);
  if (i < 8192){ int r=i>>8, k=i&255;
    float v = (r<16) ? Wpi[r*256+k] : ((r==16) ? Wv[k] : 0.f);
    Wpvb[i] = f2b(v); }
  if (i < 1024){ wr_[i] = Wih[i*1041+1024]; bsum[i] = bih[i]+bhh[i]; }
  if (i < 16384){ int a=i>>10, n=i&1023; Etab[i] = Wih[n*1041+1025+a]; }
  if (i < 32) bpv[i] = (i<16) ? bpi[i] : ((i==16) ? bv[0] : 0.f);
}

// ---------------- segment builder (LDS-staged dones, R13) ----------------
__global__ __launch_bounds__(256) void build_cols(const int* __restrict__ dones,
                                                  int* __restrict__ vt,
                                                  int* __restrict__ lens){
  extern __shared__ int dl[];            // [256 t][128 b] = 128 KB
  const int b0 = blockIdx.x * 128;
  for (int idx = threadIdx.x; idx < 256*128; idx += 256){
    int tt = idx >> 7, bb = idx & 127;
    dl[tt*128 + bb] = dones[tt*512 + b0 + bb];
  }
  __syncthreads();
  const int bb = threadIdx.x;
  if (bb >= 128) return;
  const int b = b0 + bb;
  const int colbase = (b>>1)*16 + (b&1)*8;
  int cur = 0, curpos = 0;
  for (int t = 0; t < 256; ++t){
    int isStart = (t==0) || (dl[t*128+bb] != 0);
    if (isStart){
      int nc = t>>5; if (nc>7) nc=7;      // cumulative position == t
      if (nc != cur){
        lens[colbase+cur] = curpos;
        for (int j=cur+1;j<nc;++j) lens[colbase+j]=0;
        cur = nc; curpos = 0;
      }
    }
    int rstA = (t==255) || (dl[(t==255?255:(t+1))*128+bb] != 0);
    vt[(colbase+cur)*COLCAP + curpos] = t | (1<<9) | (rstA<<10);
    curpos++;
  }
  lens[colbase+cur] = curpos;
  for (int j=cur+1;j<8;++j) lens[colbase+j]=0;
}

// ---------------- 256x256 bf16 GEMM (R17/R12: 2-phase + coalesced epi) ----
// Best-measured configuration (R17: 361us). Loop: 2-phase counted vmcnt(4),
// T2 swizzle, interior lgkm pins, two barriers/iter. Epilogue: LDS-staged
// coalesced 16B stores.
template<int K, int EPI>
__global__ __launch_bounds__(512, 2) void gemm256(
    const ushort* __restrict__ A, const ushort* __restrict__ Bm,
    ushort* __restrict__ C,
    const float* __restrict__ e0, const float* __restrict__ e1,
    const float* __restrict__ e2, const float* __restrict__ rew,
    const int* __restrict__ la){
  extern __shared__ char L[];
  const int t = threadIdx.x, w = t>>6, l = t&63, lq = l>>4, lr = l&15;
  const int wr = w>>2, wc = w&3;            // 2 x 4 wave grid
  const int lid = blockIdx.y*4 + blockIdx.x;
  const int xcd = lid & 7, jj = lid >> 3;   // XCD round-robin model
  const int m0 = (xcd*64 + (jj>>2))*256;
  const int n0 = (jj&3)*256;

  const int r0 = t>>3;
  const int c0 = (t&7) ^ (r0&7);
  const ushort* As0 = A  + (size_t)(m0 +       r0)*K + c0*8;
  const ushort* As1 = A  + (size_t)(m0 +  64 + r0)*K + c0*8;
  const ushort* As2 = A  + (size_t)(m0 + 128 + r0)*K + c0*8;
  const ushort* As3 = A  + (size_t)(m0 + 192 + r0)*K + c0*8;
  const ushort* Bs0 = Bm + (size_t)(n0 +       r0)*K + c0*8;
  const ushort* Bs1 = Bm + (size_t)(n0 +  64 + r0)*K + c0*8;
  const ushort* Bs2 = Bm + (size_t)(n0 + 128 + r0)*K + c0*8;
  const ushort* Bs3 = Bm + (size_t)(n0 + 192 + r0)*K + c0*8;

#define SA(p, ko) do{ \
    GLDS16(As0 + (ko), L + (p)*65536 +     0 + t*16); \
    GLDS16(As1 + (ko), L + (p)*65536 +  8192 + t*16); \
    GLDS16(As2 + (ko), L + (p)*65536 + 16384 + t*16); \
    GLDS16(As3 + (ko), L + (p)*65536 + 24576 + t*16); }while(0)
#define SB(p, ko) do{ \
    GLDS16(Bs0 + (ko), L + (p)*65536 + 32768 + t*16); \
    GLDS16(Bs1 + (ko), L + (p)*65536 + 40960 + t*16); \
    GLDS16(Bs2 + (ko), L + (p)*65536 + 49152 + t*16); \
    GLDS16(Bs3 + (ko), L + (p)*65536 + 57344 + t*16); }while(0)
#define LDA(p, mf, ks) (*(const bf16x8*)(L + (p)*65536 + \
    (wr*128 + (mf)*16 + lr)*128 + (((((ks)*4) + lq) ^ (lr&7))<<4)))
#define LDB(p, nf, ks) (*(const bf16x8*)(L + (p)*65536 + 32768 + \
    (wc*64 + (nf)*16 + lr)*128 + (((((ks)*4) + lq) ^ (lr&7))<<4)))

  f32x4 acc[8][4] = {};
  constexpr int NT = K/64;

  SA(0, 0); SB(0, 0);          // prologue: 8 loads in flight
  #pragma unroll
  for (int kt = 0; kt < NT; ++kt){
    const int p = kt&1;
    if (kt+1 < NT) SA(p^1, (kt+1)*64);
    __builtin_amdgcn_sched_barrier(0);
    if (kt+1 < NT) asm volatile("s_waitcnt vmcnt(4)" ::: "memory");
    else           asm volatile("s_waitcnt vmcnt(0)" ::: "memory");
    __builtin_amdgcn_s_barrier();
    __builtin_amdgcn_sched_barrier(0);
    bf16x8 af[8], bf[4];
    #pragma unroll
    for (int mf=0;mf<8;++mf) af[mf] = LDA(p, mf, 0);
    #pragma unroll
    for (int nf=0;nf<4;++nf) bf[nf] = LDB(p, nf, 0);
    asm volatile("s_waitcnt lgkmcnt(0)" ::: "memory");
    __builtin_amdgcn_sched_barrier(0);
    __builtin_amdgcn_s_setprio(1);
    #pragma unroll
    for (int mf=0;mf<8;++mf)
      #pragma unroll
      for (int nf=0;nf<4;++nf)
        acc[mf][nf] = __builtin_amdgcn_mfma_f32_16x16x32_bf16(bf[nf], af[mf], acc[mf][nf], 0,0,0);
    __builtin_amdgcn_s_setprio(0);
    if (kt+1 < NT) SB(p^1, (kt+1)*64);
    #pragma unroll
    for (int mf=0;mf<8;++mf) af[mf] = LDA(p, mf, 1);
    #pragma unroll
    for (int nf=0;nf<4;++nf) bf[nf] = LDB(p, nf, 1);
    asm volatile("s_waitcnt lgkmcnt(0)" ::: "memory");
    __builtin_amdgcn_sched_barrier(0);
    __builtin_amdgcn_s_setprio(1);
    #pragma unroll
    for (int mf=0;mf<8;++mf)
      #pragma unroll
      for (int nf=0;nf<4;++nf)
        acc[mf][nf] = __builtin_amdgcn_mfma_f32_16x16x32_bf16(bf[nf], af[mf], acc[mf][nf], 0,0,0);
    __builtin_amdgcn_s_setprio(0);
    __builtin_amdgcn_sched_barrier(0);
    __builtin_amdgcn_s_barrier();
    __builtin_amdgcn_sched_barrier(0);
  }

  // ---- epilogue: LDS-staged coalesced C-write (512B rows, slot^=row&7)
  #pragma unroll
  for (int mf=0; mf<8; ++mf){
    const int row = wr*128 + mf*16 + lr;
    const int m = m0 + row;
    float rv = 0.f; int av = 0;
    if (EPI == 2){ rv = rew[m]; av = la[m]; }
    #pragma unroll
    for (int nf=0; nf<4; ++nf){
      const int nl = wc*64 + nf*16 + lq*4;
      short4v v;
      if (EPI == 1){
        const float4 bn = *(const float4*)&e0[n0 + nl];
        #pragma unroll
        for (int r=0;r<4;++r){
          float vv = acc[mf][nf][r] + ((const float*)&bn)[r];
          vv = vv > 0.f ? vv : 0.01f*vv;
          v[r] = (short)f2b(vv);
        }
      } else {
        const float4 wv = *(const float4*)&e0[n0 + nl];
        const float4 bs = *(const float4*)&e1[n0 + nl];
        const float4 et = *(const float4*)&e2[(size_t)av*1024 + n0 + nl];
        #pragma unroll
        for (int r=0;r<4;++r){
          float vv = acc[mf][nf][r] + rv*((const float*)&wv)[r]
                   + ((const float*)&et)[r] + ((const float*)&bs)[r];
          v[r] = (short)f2b(vv);
        }
      }
      const int slot = nl >> 3;
      const int phys = slot ^ (row & 7);
      *(short4v*)(L + row*512 + phys*16 + (lq&1)*8) = v;
    }
  }
  __builtin_amdgcn_sched_barrier(0);
  asm volatile("s_waitcnt lgkmcnt(0)" ::: "memory");
  __builtin_amdgcn_s_barrier();
  __builtin_amdgcn_sched_barrier(0);
  {
    const int c16 = t & 31;
    #pragma unroll
    for (int j2=0;j2<16;++j2){
      const int row = j2*16 + (t>>5);
      const int phys = c16 ^ (row & 7);
      bf16x8 d = *(const bf16x8*)(L + row*512 + phys*16);
      *(bf16x8*)&C[(size_t)(m0+row)*1024 + n0 + c16*8] = d;
    }
  }
#undef SA
#undef SB
#undef LDA
#undef LDB
}

// ---------------- 128x128 fused gemm1 (f32 x converted in-staging) --------
// R17 race-fixed version (compiler-fenced xr; manual vmcnt only for glds).
template<int K, int EPI>
__global__ __launch_bounds__(512, 4) void gemm128o(
    const float* __restrict__ Xf, const ushort* __restrict__ Abf,
    const ushort* __restrict__ Bm, ushort* __restrict__ C,
    const float* __restrict__ e0, const float* __restrict__ e1,
    const float* __restrict__ e2, const float* __restrict__ rew,
    const int* __restrict__ la){
  __shared__ char L[65536];
  const int t = threadIdx.x, w = t>>6, l = t&63, lq = l>>4, lr = l&15;
  const int wr = w>>2, wc = w&3;            // 2 (m) x 4 (n) wave grid
  const int lid = blockIdx.y*8 + blockIdx.x;
  const int xcd = lid & 7, j = lid >> 3;    // XCD round-robin model
  const int m0 = (xcd*128 + (j>>3))*128;
  const int n0 = (j&7)*128;

  const int r0 = t>>3;
  const int c0 = (t&7) ^ (r0&7);
  const ushort* As0 = Abf + (size_t)(m0 +      r0)*K + c0*8;   // EPI==2 only
  const ushort* As1 = Abf + (size_t)(m0 + 64 + r0)*K + c0*8;
  const ushort* Bs0 = Bm + (size_t)(n0 +      r0)*K + c0*8;
  const ushort* Bs1 = Bm + (size_t)(n0 + 64 + r0)*K + c0*8;
  const float* xp = Xf + (size_t)(m0 + (t>>2))*512 + (t&3)*16;

#define STGA(p, ko) do{ \
    GLDS16(As0 + (ko), L + (p)*32768 +        t*16); \
    GLDS16(As1 + (ko), L + (p)*32768 +  8192 + t*16); }while(0)
#define STGB(p, ko) do{ \
    GLDS16(Bs0 + (ko), L + (p)*32768 + 16384 + t*16); \
    GLDS16(Bs1 + (ko), L + (p)*32768 + 24576 + t*16); }while(0)
#define LDA(p, mf, ks) (*(const bf16x8*)(L + (p)*32768 + \
    (wr*64 + (mf)*16 + lr)*128 + (((((ks)*4) + lq) ^ (lr&7))<<4)))
#define LDB(p, nf, ks) (*(const bf16x8*)(L + (p)*32768 + 16384 + \
    (wc*32 + (nf)*16 + lr)*128 + (((((ks)*4) + lq) ^ (lr&7))<<4)))
#define WRA(p) do{ \
    const int rr = t>>2, cc = t&3; \
    _Pragma("unroll") \
    for (int jw=0;jw<2;++jw){ \
      bf16x8 v; \
      float4 u0 = xr[2*jw], u1 = xr[2*jw+1]; \
      v[0]=(short)f2b(u0.x); v[1]=(short)f2b(u0.y); \
      v[2]=(short)f2b(u0.z); v[3]=(short)f2b(u0.w); \
      v[4]=(short)f2b(u1.x); v[5]=(short)f2b(u1.y); \
      v[6]=(short)f2b(u1.z); v[7]=(short)f2b(u1.w); \
      *(bf16x8*)(L + (p)*32768 + rr*128 + (((2*cc+jw)^(rr&7))<<4)) = v; \
    }}while(0)

  f32x4 acc[4][2] = {};
  constexpr int NT = K/64;
  float4 xr[4];

  if (EPI == 1){
    #pragma unroll
    for (int jx=0;jx<4;++jx) xr[jx] = *(const float4*)(xp + jx*4);
    STGB(0, 0);
    __builtin_amdgcn_sched_barrier(0);
    WRA(0);                                  // compiler waits for xr itself
    asm volatile("s_waitcnt lgkmcnt(0)" ::: "memory");
    asm volatile("s_waitcnt vmcnt(0)" ::: "memory");   // B glds landed
    __builtin_amdgcn_s_barrier();
    __builtin_amdgcn_sched_barrier(0);
  } else {
    STGA(0, 0); STGB(0, 0);
  }

  for (int kt = 0; kt < NT; ++kt){
    const int p = kt&1, q = p^1;
    const bool pf = (kt+1 < NT);
    if (EPI == 1){
      if (pf){
        const float* xn = xp + (kt+1)*64;
        #pragma unroll
        for (int jx=0;jx<4;++jx) xr[jx] = *(const float4*)(xn + jx*4);
        STGB(q, (kt+1)*64);
      }
      __builtin_amdgcn_sched_barrier(0);
      #pragma unroll
      for (int ks=0; ks<2; ++ks){
        bf16x8 af[4], bf[2];
        #pragma unroll
        for (int mf=0;mf<4;++mf) af[mf] = LDA(p, mf, ks);
        #pragma unroll
        for (int nf=0;nf<2;++nf) bf[nf] = LDB(p, nf, ks);
        asm volatile("s_waitcnt lgkmcnt(0)" ::: "memory");
        __builtin_amdgcn_sched_barrier(0);
        __builtin_amdgcn_s_setprio(1);
        #pragma unroll
        for (int mf=0;mf<4;++mf)
          #pragma unroll
          for (int nf=0;nf<2;++nf)
            acc[mf][nf] = __builtin_amdgcn_mfma_f32_16x16x32_bf16(bf[nf], af[mf], acc[mf][nf], 0,0,0);
        __builtin_amdgcn_s_setprio(0);
      }
      __builtin_amdgcn_sched_barrier(0);
      if (pf){
        WRA(q);                              // compiler waits for xr itself
        asm volatile("s_waitcnt lgkmcnt(0)" ::: "memory");
      } else {
        asm volatile("s_waitcnt lgkmcnt(0)" ::: "memory");
      }
      asm volatile("s_waitcnt vmcnt(0)" ::: "memory");  // B(q) glds landed
      __builtin_amdgcn_s_barrier();
      __builtin_amdgcn_sched_barrier(0);
    } else {
      if (pf){ STGA(q, (kt+1)*64); STGB(q, (kt+1)*64); }
      __builtin_amdgcn_sched_barrier(0);
      if (pf) asm volatile("s_waitcnt vmcnt(4)" ::: "memory");
      else    asm volatile("s_waitcnt vmcnt(0)" ::: "memory");
      __builtin_amdgcn_s_barrier();
      __builtin_amdgcn_sched_barrier(0);
      #pragma unroll
      for (int ks=0; ks<2; ++ks){
        bf16x8 af[4], bf[2];
        #pragma unroll
        for (int mf=0;mf<4;++mf) af[mf] = LDA(p, mf, ks);
        #pragma unroll
        for (int nf=0;nf<2;++nf) bf[nf] = LDB(p, nf, ks);
        asm volatile("s_waitcnt lgkmcnt(0)" ::: "memory");
        __builtin_amdgcn_sched_barrier(0);
        __builtin_amdgcn_s_setprio(1);
        #pragma unroll
        for (int mf=0;mf<4;++mf)
          #pragma unroll
          for (int nf=0;nf<2;++nf)
            acc[mf][nf] = __builtin_amdgcn_mfma_f32_16x16x32_bf16(bf[nf], af[mf], acc[mf][nf], 0,0,0);
        __builtin_amdgcn_s_setprio(0);
      }
      __builtin_amdgcn_sched_barrier(0);
      __builtin_amdgcn_s_barrier();
      __builtin_amdgcn_sched_barrier(0);
    }
  }

  // ---- epilogue: LDS-staged coalesced C-write (256B rows)
  #pragma unroll
  for (int mf=0; mf<4; ++mf){
    const int row = wr*64 + mf*16 + lr;
    const int m = m0 + row;
    float rv = 0.f; int av = 0;
    if (EPI == 2){ rv = rew[m]; av = la[m]; }
    #pragma unroll
    for (int nf=0; nf<2; ++nf){
      const int nl = wc*32 + nf*16 + lq*4;
      short4v v;
      if (EPI == 1){
        const float4 bn = *(const float4*)&e0[n0 + nl];
        #pragma unroll
        for (int r=0;r<4;++r){
          float vv = acc[mf][nf][r] + ((const float*)&bn)[r];
          vv = vv > 0.f ? vv : 0.01f*vv;
          v[r] = (short)f2b(vv);
        }
      } else {
        const float4 wv = *(const float4*)&e0[n0 + nl];
        const float4 bs = *(const float4*)&e1[n0 + nl];
        const float4 et = *(const float4*)&e2[(size_t)av*1024 + n0 + nl];
        #pragma unroll
        for (int r=0;r<4;++r){
          float vv = acc[mf][nf][r] + rv*((const float*)&wv)[r]
                   + ((const float*)&et)[r] + ((const float*)&bs)[r];
          v[r] = (short)f2b(vv);
        }
      }
      const int slot = nl >> 3;
      const int phys = slot ^ (row & 15);
      *(short4v*)(L + row*256 + phys*16 + (lq&1)*8) = v;
    }
  }
  __builtin_amdgcn_sched_barrier(0);
  asm volatile("s_waitcnt lgkmcnt(0)" ::: "memory");
  __builtin_amdgcn_s_barrier();
  __builtin_amdgcn_sched_barrier(0);
  {
    const int c16 = t & 15;
    #pragma unroll
    for (int jj=0;jj<4;++jj){
      const int row = jj*32 + (t>>4);
      const int phys = c16 ^ (row & 15);
      bf16x8 d = *(const bf16x8*)(L + row*256 + phys*16);
      *(bf16x8*)&C[(size_t)(m0+row)*1024 + n0 + c16*8] = d;
    }
  }
#undef STGA
#undef STGB
#undef LDA
#undef LDB
#undef WRA
}

// ---------------- recurrent LSTM kernel (segment-parallel) ----------------
#define LW_FR 18
#define HB0 (8*LW_FR*1024)
__global__ __launch_bounds__(512, 2) void lstm_seq(
    const ushort* __restrict__ Whhb, const ushort* __restrict__ gx,
    ushort* __restrict__ hsout, const int* __restrict__ vt,
    const int* __restrict__ lens){
  extern __shared__ char smem[];
  ushort* wlds = (ushort*)smem;
  char* hb = smem + HB0;                 // 16 cols x 256 bf16, XOR-swizzled
  const int t = threadIdx.x, w = t>>6, l = t&63, lq = l>>4, lr = l&15;
  const int g = blockIdx.x;
  const int bcol = 2*g + (lr>>3);        // batch of column lr
  const int cgl = g*16 + lr;             // global column id

  // register weight frags: m<2 -> k0..4 ; m>=2 -> k0..5   (m = gate*2+hi)
  bf16x8 wf[8][6];
  #pragma unroll
  for (int m=0;m<8;++m){
    const size_t rb = (size_t)((m>>1)*256 + w*32 + (m&1)*16 + lr)*256 + lq*8;
    #pragma unroll
    for (int k=0;k<6;++k){
      if (k < ((m<2)?5:6)) wf[m][k] = *(const bf16x8*)&Whhb[rb + (size_t)k*32];
    }
  }
  // Pin: forbid rematerializing these loads inside the step loop.
  #pragma unroll
  for (int m=0;m<8;++m)
    #pragma unroll
    for (int k=0;k<6;++k)
      if (k < ((m<2)?5:6)) asm volatile("" : "+v"(wf[m][k]));

  // LDS weight frags: m<2 -> k5,6,7 ; m>=2 -> k6,7
  #pragma unroll
  for (int m=0;m<8;++m){
    const size_t rb = (size_t)((m>>1)*256 + w*32 + (m&1)*16 + lr)*256 + lq*8;
    #pragma unroll
    for (int kk=0;kk<3;++kk){
      if (kk < ((m<2)?3:2)){
        const int k  = (m<2)?(5+kk):(6+kk);
        const int fi = (m<2)?(m*3+kk):(6+(m-2)*2+kk);
        bf16x8 v = *(const bf16x8*)&Whhb[rb + (size_t)k*32];
        *(bf16x8*)((char*)wlds + ((w*LW_FR + fi)*1024 + l*16)) = v;
      }
    }
  }
  { bf16x8 z = {0,0,0,0,0,0,0,0}; *(bf16x8*)(hb + t*16) = z; }  // zero h

#define LDSFRAG(m,kf) (*(const bf16x8*)((char*)wlds + ((w*LW_FR + ((m)<2 ? ((m)*3+((kf)-5)) : (6+((m)-2)*2+((kf)-6))))*1024 + l*16)))
#define WFRAG(m,kf) (((kf) < (((m)<2)?5:6)) ? wf[m][kf] : LDSFRAG(m,kf))
#define HVREAD(kf) (*(const bf16x8*)(hb + ((lr*512 + (kf)*64 + lq*16) ^ ((lr&7)<<4))))

  const int lenc = lens[cgl];
  int blkLen = 0;
  for (int j=0;j<16;++j){ int v = lens[g*16+j]; blkLen = v>blkLen ? v : blkLen; }
  const int* vtc = vt + (size_t)cgl*COLCAP;
#define ENTW(j) (((j) < lenc) ? vtc[j] : DEADW)

  int e0 = ENTW(0), e1 = ENTW(1);
  const int goff = w*32 + lq*4;
  float c_[2][4] = {};
  uint2 gi[2], gg[2];
  {
    const ushort* gr = gx + ((size_t)((e0 & 511)*512 + bcol))*1024 + goff;
    gi[0]=*(const uint2*)(gr+  0); gi[1]=*(const uint2*)(gr+ 16);
    gg[0]=*(const uint2*)(gr+512); gg[1]=*(const uint2*)(gr+528);
  }
  __syncthreads();

  for (int k = 0; k < blkLen; ++k){
    const int e2 = ENTW(k+2);
    const ushort* grow0 = gx + ((size_t)((e0 & 511)*512 + bcol))*1024 + goff;
    uint2 gf0=*(const uint2*)(grow0+256), gf1=*(const uint2*)(grow0+272);
    uint2 go0=*(const uint2*)(grow0+768), go1=*(const uint2*)(grow0+784);
    // ---- pass 1: i and g gates (m-frags 0,1,4,5)
    f32x4 ai0={},ai1={},ag0={},ag1={};
    #pragma unroll
    for (int kf=0;kf<8;++kf){
      bf16x8 hv = HVREAD(kf);
      ai0 = __builtin_amdgcn_mfma_f32_16x16x32_bf16(WFRAG(0,kf), hv, ai0, 0,0,0);
      ai1 = __builtin_amdgcn_mfma_f32_16x16x32_bf16(WFRAG(1,kf), hv, ai1, 0,0,0);
      ag0 = __builtin_amdgcn_mfma_f32_16x16x32_bf16(WFRAG(4,kf), hv, ag0, 0,0,0);
      ag1 = __builtin_amdgcn_mfma_f32_16x16x32_bf16(WFRAG(5,kf), hv, ag1, 0,0,0);
    }
    float tig[2][4];
    #pragma unroll
    for (int hi=0;hi<2;++hi){
      uint2 ui = gi[hi], ug = gg[hi];
      float xi[4] = { b2f((unsigned short)(ui.x&0xffff)), b2f((unsigned short)(ui.x>>16)),
                      b2f((unsigned short)(ui.y&0xffff)), b2f((unsigned short)(ui.y>>16)) };
      float xg[4] = { b2f((unsigned short)(ug.x&0xffff)), b2f((unsigned short)(ug.x>>16)),
                      b2f((unsigned short)(ug.y&0xffff)), b2f((unsigned short)(ug.y>>16)) };
      #pragma unroll
      for (int r=0;r<4;++r){
        float iv = (hi ? ai1[r] : ai0[r]) + xi[r];
        float gv = (hi ? ag1[r] : ag0[r]) + xg[r];
        tig[hi][r] = sigf(iv) * tanhf_(gv);
      }
    }
    {
      const ushort* grow1 = gx + ((size_t)((e1 & 511)*512 + bcol))*1024 + goff;
      gi[0]=*(const uint2*)(grow1+  0); gi[1]=*(const uint2*)(grow1+ 16);
      gg[0]=*(const uint2*)(grow1+512); gg[1]=*(const uint2*)(grow1+528);
    }
    // ---- pass 2: f and o gates (m-frags 2,3,6,7)
    f32x4 af0={},af1={},ao0={},ao1={};
    #pragma unroll
    for (int kf=0;kf<8;++kf){
      bf16x8 hv = HVREAD(kf);
      af0 = __builtin_amdgcn_mfma_f32_16x16x32_bf16(WFRAG(2,kf), hv, af0, 0,0,0);
      af1 = __builtin_amdgcn_mfma_f32_16x16x32_bf16(WFRAG(3,kf), hv, af1, 0,0,0);
      ao0 = __builtin_amdgcn_mfma_f32_16x16x32_bf16(WFRAG(6,kf), hv, ao0, 0,0,0);
      ao1 = __builtin_amdgcn_mfma_f32_16x16x32_bf16(WFRAG(7,kf), hv, ao1, 0,0,0);
    }
    uint2 hpk[2];
    #pragma unroll
    for (int hi=0;hi<2;++hi){
      uint2 uf = hi ? gf1 : gf0, uo = hi ? go1 : go0;
      float xf[4] = { b2f((unsigned short)(uf.x&0xffff)), b2f((unsigned short)(uf.x>>16)),
                      b2f((unsigned short)(uf.y&0xffff)), b2f((unsigned short)(uf.y>>16)) };
      float xo[4] = { b2f((unsigned short)(uo.x&0xffff)), b2f((unsigned short)(uo.x>>16)),
                      b2f((unsigned short)(uo.y&0xffff)), b2f((unsigned short)(uo.y>>16)) };
      float hv[4];
      #pragma unroll
      for (int r=0;r<4;++r){
        float fv = (hi ? af1[r] : af0[r]) + xf[r];
        float ov = (hi ? ao1[r] : ao0[r]) + xo[r];
        float c = sigf(fv)*c_[hi][r] + tig[hi][r];
        c_[hi][r] = c;
        hv[r] = sigf(ov) * tanhf_(c);
      }
      hpk[hi].x = (unsigned)f2b(hv[0]) | ((unsigned)f2b(hv[1])<<16);
      hpk[hi].y = (unsigned)f2b(hv[2]) | ((unsigned)f2b(hv[3])<<16);
    }
    // ---- store hs (pre-mask) if active
    if (e0 & 512){
      ushort* hp = hsout + ((size_t)((e0 & 511)*512 + bcol))*256 + goff;
      *(uint2*)(hp +  0) = hpk[0];
      *(uint2*)(hp + 16) = hpk[1];
    }
    // ---- segment-boundary reset
    if (e0 & 1024){
      hpk[0].x=0; hpk[0].y=0; hpk[1].x=0; hpk[1].y=0;
      #pragma unroll
      for (int hi=0;hi<2;++hi)
        #pragma unroll
        for (int r=0;r<4;++r) c_[hi][r]=0.f;
    }
    e0 = e1; e1 = e2;
    BARRIER_LDS();   // all h reads of this step complete (no vmcnt drain)
    *(uint2*)(hb + ((lr*512 + w*64 +  0 + lq*8) ^ ((lr&7)<<4))) = hpk[0];
    *(uint2*)(hb + ((lr*512 + w*64 + 32 + lq*8) ^ ((lr&7)<<4))) = hpk[1];
    BARRIER_LDS();   // new h visible (no vmcnt drain)
  }
}

// ---------------- head: logits/values ----------------
__global__ __launch_bounds__(256) void head(
    const ushort* __restrict__ hs, const ushort* __restrict__ Wpv,
    const float* __restrict__ bpv, float* __restrict__ out){
  const int t = threadIdx.x, w = t>>6, l = t&63, lq = l>>4, lr = l&15;
  const int m0 = blockIdx.x*64 + w*16;
  f32x4 acc[2] = {};
  #pragma unroll
  for (int kf=0;kf<8;++kf){
    bf16x8 a = *(const bf16x8*)&hs[(size_t)(m0+lr)*256 + kf*32 + lq*8];
    #pragma unroll
    for (int j=0;j<2;++j){
      bf16x8 b = *(const bf16x8*)&Wpv[(size_t)(j*16+lr)*256 + kf*32 + lq*8];
      acc[j] = __builtin_amdgcn_mfma_f32_16x16x32_bf16(a, b, acc[j], 0,0,0);
    }
  }
  #pragma unroll
  for (int j=0;j<2;++j){
    const int n = j*16 + lr;
    if (n > 16) continue;
    const float bn = bpv[n];
    #pragma unroll
    for (int r=0;r<4;++r){
      const int m = m0 + lq*4 + r;
      float v = acc[j][r] + bn;
      if (n < 16) out[(size_t)m*16 + n] = v;
      else        out[(size_t)LOGOFF + m] = v;
    }
  }
}

// ---------------- launch ----------------
extern "C" void kernel_launch(void* const* d_in, const int* in_sizes, int n_in,
                              void* d_out, int out_size, void* d_ws, size_t ws_size,
                              hipStream_t stream) {
  const float* x    = (const float*)d_in[0];
  const float* rew  = (const float*)d_in[1];
  const float* W1   = (const float*)d_in[3];
  const float* b1   = (const float*)d_in[4];
  const float* Wih  = (const float*)d_in[5];
  const float* bih  = (const float*)d_in[6];
  const float* Whh  = (const float*)d_in[7];
  const float* bhh  = (const float*)d_in[8];
  const float* Wpi  = (const float*)d_in[9];
  const float* bpi  = (const float*)d_in[10];
  const float* Wv   = (const float*)d_in[11];
  const float* bv   = (const float*)d_in[12];
  const int*   la   = (const int*)d_in[13];
  const int*   dns  = (const int*)d_in[14];
  float* out = (float*)d_out;
  char* ws = (char*)d_ws;

  int*    vt   = (int*)(ws + 0LL);             // 4096 cols x 256 x 4B = 4 MB
  int*    lens = (int*)(ws + 4194304LL);       // 16 KB
  ushort* h1   = (ushort*)(ws + 134217728LL);
  ushort* gx   = (ushort*)(ws + 402653184LL);
  ushort* hs   = (ushort*)(ws + 671088640LL);
  ushort* W1b  = (ushort*)(ws + 738197504LL);
  ushort* Awb  = (ushort*)(ws + 739246080LL);
  ushort* Whhb = (ushort*)(ws + 741343232LL);
  ushort* Wpvb = (ushort*)(ws + 741867520LL);
  float*  wr_  = (float*)(ws + 741883904LL);
  float*  bsum = (float*)(ws + 741888000LL);
  float*  Etab = (float*)(ws + 741892096LL);
  float*  bpv  = (float*)(ws + 741957632LL);

  (void)hipFuncSetAttribute((const void*)lstm_seq,
                            hipFuncAttributeMaxDynamicSharedMemorySize, 155648);
  (void)hipFuncSetAttribute((const void*)build_cols,
                            hipFuncAttributeMaxDynamicSharedMemorySize, 131072);
  auto g2 = &gemm256<1024,2>;
  (void)hipFuncSetAttribute((const void*)g2,
                            hipFuncAttributeMaxDynamicSharedMemorySize, 131072);

  prep_w<<<4096, 256, 0, stream>>>(W1, Wih, bih, Whh, bhh, Wpi, bpi, Wv, bv,
                                   W1b, Awb, Whhb, Wpvb, wr_, bsum, Etab, bpv);
  build_cols<<<4, 256, 131072, stream>>>(dns, vt, lens);
  gemm128o<512,1><<<dim3(8,1024), 512, 0, stream>>>(x, nullptr, W1b, h1, b1,
                                                    nullptr, nullptr, nullptr, nullptr);
  gemm256<1024,2><<<dim3(4,512), 512, 131072, stream>>>(h1, Awb, gx, wr_,
                                                        bsum, Etab, rew, la);
  lstm_seq<<<256, 512, 155648, stream>>>(Whhb, gx, hs, vt, lens);
  head<<<2048, 256, 0, stream>>>(hs, Wpvb, bpv, out);
}